// Round 7
// baseline (1088.578 us; speedup 1.0000x reference)
//
#include <hip/hip_runtime.h>

// 2-layer hetero GraphSAGE, fp32 compute, bf16 gather tables, bucketed CSR build,
// persistent-weight register-tiled combines. ALL tile kernels use STATIC LDS:
// dynamic (extern __shared__) LDS made the compiler balloon to 256 VGPR + spill
// (R6: 540MB scratch FETCH/dispatch). Layer-2 combines fused via static-LDS
// dual-input kernel (49 KB); L1-buys stays two-pass (would need 73 KB).

using u16 = unsigned short;
using u32 = unsigned int;

__device__ __forceinline__ u16 bf16r(float f) {            // round-to-nearest-even
    u32 b = __float_as_uint(f);
    b += 0x7fffu + ((b >> 16) & 1u);
    return (u16)(b >> 16);
}
__device__ __forceinline__ float bflo(u32 u) { return __uint_as_float(u << 16); }
__device__ __forceinline__ float bfhi(u32 u) { return __uint_as_float(u & 0xffff0000u); }

#define BSH 8          // bucket = key >> BSH, 256 node ids per bucket
#define MAXB 512       // max buckets per direction (NU=100000 -> 391)
#define CHUNK 4096     // edges per partition block
#define RPT 16         // CHUNK / 256

// ---- pass A: coarse bucket histograms, both directions fused ----
__global__ __launch_bounds__(256) void k_histA(const int* __restrict__ esrc,
                                               const int* __restrict__ edst,
                                               int* __restrict__ bcntP,
                                               int* __restrict__ bcntU,
                                               int NBP, int NBU, int E) {
    __shared__ int hP[MAXB];
    __shared__ int hU[MAXB];
    int tid = threadIdx.x;
    for (int i = tid; i < MAXB; i += 256) { hP[i] = 0; hU[i] = 0; }
    __syncthreads();
    int E4 = E >> 2;
    const int4* s4 = (const int4*)esrc;
    const int4* d4 = (const int4*)edst;
    int stride = gridDim.x * 256;
    for (int i = blockIdx.x * 256 + tid; i < E4; i += stride) {
        int4 s = s4[i], d = d4[i];
        atomicAdd(&hU[s.x >> BSH], 1); atomicAdd(&hU[s.y >> BSH], 1);
        atomicAdd(&hU[s.z >> BSH], 1); atomicAdd(&hU[s.w >> BSH], 1);
        atomicAdd(&hP[d.x >> BSH], 1); atomicAdd(&hP[d.y >> BSH], 1);
        atomicAdd(&hP[d.z >> BSH], 1); atomicAdd(&hP[d.w >> BSH], 1);
    }
    if (blockIdx.x == 0 && tid < (E & 3)) {
        int e = E4 * 4 + tid;
        atomicAdd(&hU[esrc[e] >> BSH], 1);
        atomicAdd(&hP[edst[e] >> BSH], 1);
    }
    __syncthreads();
    for (int i = tid; i < NBP; i += 256) if (hP[i]) atomicAdd(&bcntP[i], hP[i]);
    for (int i = tid; i < NBU; i += 256) if (hU[i]) atomicAdd(&bcntU[i], hU[i]);
}

// ---- scan bucket counts -> bases[NB+1] and working cursor[NB]; block 0 = P, 1 = U ----
__global__ __launch_bounds__(256) void k_scanBuckets(const int* __restrict__ cntP,
                                                     int* __restrict__ basesP,
                                                     int* __restrict__ curP, int NBP,
                                                     const int* __restrict__ cntU,
                                                     int* __restrict__ basesU,
                                                     int* __restrict__ curU, int NBU) {
    const int* cnt; int* bases; int* cur; int NB;
    if (blockIdx.x == 0) { cnt = cntP; bases = basesP; cur = curP; NB = NBP; }
    else                 { cnt = cntU; bases = basesU; cur = curU; NB = NBU; }
    __shared__ int sA[MAXB];
    __shared__ int sB[MAXB];
    int tid = threadIdx.x;
    int v0 = (tid < NB) ? cnt[tid] : 0;
    int v1 = (tid + 256 < NB) ? cnt[tid + 256] : 0;
    sA[tid] = v0; sA[tid + 256] = v1;
    __syncthreads();
    int* src = sA; int* dst = sB;
    for (int off = 1; off < MAXB; off <<= 1) {
        dst[tid] = src[tid] + ((tid >= off) ? src[tid - off] : 0);
        int i2 = tid + 256;
        dst[i2] = src[i2] + ((i2 >= off) ? src[i2 - off] : 0);
        __syncthreads();
        int* t = src; src = dst; dst = t;
    }
    if (tid < NB)       { bases[tid] = src[tid] - v0;             cur[tid] = src[tid] - v0; }
    if (tid + 256 < NB) { bases[tid + 256] = src[tid + 256] - v1; cur[tid + 256] = src[tid + 256] - v1; }
    if (tid == 0) bases[NB] = src[MAXB - 1];
}

// ---- pass B: partition edges into bucket-ordered (key,payload) pairs, coalesced flush ----
__global__ __launch_bounds__(256) void k_partition(const int* __restrict__ keys,
                                                   const int* __restrict__ payload,
                                                   int* __restrict__ cursor,
                                                   uint2* __restrict__ pairs,
                                                   int NB, int E) {
    __shared__ int hist[MAXB];
    __shared__ int sA[MAXB];
    __shared__ int sB[MAXB];
    __shared__ int bx[MAXB];
    __shared__ int gbase[MAXB];
    __shared__ uint2 prs[CHUNK];
    int tid = threadIdx.x;
    int i0 = blockIdx.x * CHUNK;
    int count = min(CHUNK, E - i0);
    for (int i = tid; i < MAXB; i += 256) hist[i] = 0;
    __syncthreads();
    int keyr[RPT], payr[RPT], rankr[RPT];
#pragma unroll
    for (int r = 0; r < RPT; ++r) {
        int idx = r * 256 + tid;
        if (idx < count) {
            int k = keys[i0 + idx];
            keyr[r] = k;
            payr[r] = payload[i0 + idx];
            rankr[r] = atomicAdd(&hist[k >> BSH], 1);
        } else keyr[r] = -1;
    }
    __syncthreads();
    // exclusive scan of hist -> bx (ping-pong, 512 wide)
    sA[tid] = hist[tid]; sA[tid + 256] = hist[tid + 256];
    __syncthreads();
    int* src = sA; int* dst = sB;
    for (int off = 1; off < MAXB; off <<= 1) {
        dst[tid] = src[tid] + ((tid >= off) ? src[tid - off] : 0);
        int i2 = tid + 256;
        dst[i2] = src[i2] + ((i2 >= off) ? src[i2 - off] : 0);
        __syncthreads();
        int* t = src; src = dst; dst = t;
    }
    bx[tid] = src[tid] - hist[tid];
    bx[tid + 256] = src[tid + 256] - hist[tid + 256];
    __syncthreads();
    for (int b = tid; b < NB; b += 256) {
        int c = hist[b];
        gbase[b] = c ? atomicAdd(&cursor[b], c) : 0;
    }
    // stage into LDS in bucket order
#pragma unroll
    for (int r = 0; r < RPT; ++r) {
        if (keyr[r] >= 0)
            prs[bx[keyr[r] >> BSH] + rankr[r]] = make_uint2((u32)keyr[r], (u32)payr[r]);
    }
    __syncthreads();
    // coalesced segment copy-out
    for (int j = tid; j < count; j += 256) {
        uint2 pr = prs[j];
        int b = pr.x >> BSH;
        pairs[gbase[b] + (j - bx[b])] = pr;
    }
}

// ---- pass C: per-bucket fine fill -> nbr, deg, ptr(start); both directions fused ----
__global__ __launch_bounds__(256) void k_bucketFill(
    const uint2* __restrict__ pairsP, const int* __restrict__ basesP, int NBP,
    int* __restrict__ nbr_p, int* __restrict__ deg_p, int* __restrict__ ptr_p, int NP,
    const uint2* __restrict__ pairsU, const int* __restrict__ basesU, int NBU,
    int* __restrict__ nbr_u, int* __restrict__ deg_u, int* __restrict__ ptr_u, int NU) {
    const uint2* pairs; const int* bases; int* nbr; int* deg; int* ptr; int N; int bucket;
    if ((int)blockIdx.x < NBP) {
        pairs = pairsP; bases = basesP; nbr = nbr_p; deg = deg_p; ptr = ptr_p; N = NP;
        bucket = blockIdx.x;
    } else {
        pairs = pairsU; bases = basesU; nbr = nbr_u; deg = deg_u; ptr = ptr_u; N = NU;
        bucket = blockIdx.x - NBP;
    }
    int tid = threadIdx.x;
    int base = bases[bucket];
    int cnt = bases[bucket + 1] - base;
    __shared__ int h[256];
    __shared__ int s[256];
    __shared__ int cur[256];
    h[tid] = 0;
    __syncthreads();
    for (int j = tid; j < cnt; j += 256) atomicAdd(&h[pairs[base + j].x & 255], 1);
    __syncthreads();
    int d = h[tid];
    s[tid] = d;
    __syncthreads();
    for (int off = 1; off < 256; off <<= 1) {
        int v = (tid >= off) ? s[tid - off] : 0;
        __syncthreads();
        s[tid] += v;
        __syncthreads();
    }
    int excl = s[tid] - d;
    int node = bucket * 256 + tid;
    if (node < N) { deg[node] = d; ptr[node] = base + excl; }
    cur[tid] = excl;
    __syncthreads();
    for (int j = tid; j < cnt; j += 256) {
        uint2 pr = pairs[base + j];
        int pos = atomicAdd(&cur[pr.x & 255], 1);
        nbr[base + pos] = pr.y;
    }
}

// ---------------- fp32 table -> bf16 shadow, 8 elems/thread ----------------
__global__ __launch_bounds__(256) void k_cast8(const float* __restrict__ x,
                                               u16* __restrict__ y, int n8) {
    int i = blockIdx.x * 256 + threadIdx.x;
    if (i >= n8) return;
    const float4* x4 = (const float4*)x;
    float4 a = x4[i * 2], b = x4[i * 2 + 1];
    uint4 o;
    o.x = (u32)bf16r(a.x) | ((u32)bf16r(a.y) << 16);
    o.y = (u32)bf16r(a.z) | ((u32)bf16r(a.w) << 16);
    o.z = (u32)bf16r(b.x) | ((u32)bf16r(b.y) << 16);
    o.w = (u32)bf16r(b.z) | ((u32)bf16r(b.w) << 16);
    ((uint4*)y)[i] = o;
}

// ------- single-direction gather-mean; wave per node, 8 lanes per bf16 row -------
__global__ __launch_bounds__(256) void k_gather1(const u16* __restrict__ y,
                                                 const int* __restrict__ nbr,
                                                 const int* __restrict__ stp,
                                                 const int* __restrict__ degp,
                                                 float* __restrict__ agg, int N) {
    int n = (blockIdx.x * 256 + threadIdx.x) >> 6;
    int lane = threadIdx.x & 63;
    if (n >= N) return;
    const int q = lane >> 3, t = lane & 7;
    const int d = degp[n];
    int j = stp[n];
    const int end = j + d;
    float a0=0,a1=0,a2=0,a3=0,a4=0,a5=0,a6=0,a7=0;
    float b0=0,b1=0,b2=0,b3=0,b4=0,b5=0,b6=0,b7=0;
    for (; j + 16 <= end; j += 16) {
        int g0 = nbr[j + q], g1 = nbr[j + 8 + q];
        uint4 v0 = *(const uint4*)(y + g0 * 64 + t * 8);
        uint4 v1 = *(const uint4*)(y + g1 * 64 + t * 8);
        a0 += bflo(v0.x); a1 += bfhi(v0.x); a2 += bflo(v0.y); a3 += bfhi(v0.y);
        a4 += bflo(v0.z); a5 += bfhi(v0.z); a6 += bflo(v0.w); a7 += bfhi(v0.w);
        b0 += bflo(v1.x); b1 += bfhi(v1.x); b2 += bflo(v1.y); b3 += bfhi(v1.y);
        b4 += bflo(v1.z); b5 += bfhi(v1.z); b6 += bflo(v1.w); b7 += bfhi(v1.w);
    }
    for (; j + 8 <= end; j += 8) {
        int g0 = nbr[j + q];
        uint4 v0 = *(const uint4*)(y + g0 * 64 + t * 8);
        a0 += bflo(v0.x); a1 += bfhi(v0.x); a2 += bflo(v0.y); a3 += bfhi(v0.y);
        a4 += bflo(v0.z); a5 += bfhi(v0.z); a6 += bflo(v0.w); a7 += bfhi(v0.w);
    }
    if (j + q < end) {
        int g0 = nbr[j + q];
        uint4 v0 = *(const uint4*)(y + g0 * 64 + t * 8);
        a0 += bflo(v0.x); a1 += bfhi(v0.x); a2 += bflo(v0.y); a3 += bfhi(v0.y);
        a4 += bflo(v0.z); a5 += bfhi(v0.z); a6 += bflo(v0.w); a7 += bfhi(v0.w);
    }
    a0 += b0; a1 += b1; a2 += b2; a3 += b3; a4 += b4; a5 += b5; a6 += b6; a7 += b7;
#pragma unroll
    for (int m = 8; m < 64; m <<= 1) {
        a0 += __shfl_xor(a0, m, 64); a1 += __shfl_xor(a1, m, 64);
        a2 += __shfl_xor(a2, m, 64); a3 += __shfl_xor(a3, m, 64);
        a4 += __shfl_xor(a4, m, 64); a5 += __shfl_xor(a5, m, 64);
        a6 += __shfl_xor(a6, m, 64); a7 += __shfl_xor(a7, m, 64);
    }
    if (q == 0) {
        float dinv = 1.0f / (float)max(d, 1);
        float* dstp = agg + n * 64 + t * 8;
        *(float4*)dstp       = make_float4(a0 * dinv, a1 * dinv, a2 * dinv, a3 * dinv);
        *(float4*)(dstp + 4) = make_float4(a4 * dinv, a5 * dinv, a6 * dinv, a7 * dinv);
    }
}

// ======= persistent-weight register-tiled combine, single input (STATIC LDS) =======
// h = act( (PRE?pre:0) + (BIAS?b:0) + x@W );  STORE=0 -> only bf16 emit
#define FMA_ROW(ACC, O, W4) \
    ACC[0] += (O) * (W4).x; ACC[1] += (O) * (W4).y; \
    ACC[2] += (O) * (W4).z; ACC[3] += (O) * (W4).w;

template <int K, int ROWS, bool RELU, bool EMIT, bool PRE, bool BIAS, bool STORE>
__global__ __launch_bounds__(256) void k_ctile(const float* __restrict__ pre,
                                               const float* __restrict__ bias,
                                               const float* __restrict__ x,
                                               const float* __restrict__ W,
                                               float* __restrict__ h,
                                               u16* __restrict__ hbf, int N) {
    constexpr int RR = ROWS / 16;
    constexpr int STRIDE = K + 4;
    constexpr int KF4 = K / 4;
    __shared__ float Ws[K * 64];
    __shared__ float op[ROWS * STRIDE];
    const int tid = threadIdx.x;
    for (int i = tid; i < K * 16; i += 256)
        ((float4*)Ws)[i] = ((const float4*)W)[i];
    const int c4 = (tid & 15) * 4;
    const int rb = (tid >> 4) * RR;
    float bx_ = 0.f, by_ = 0.f, bz_ = 0.f, bw_ = 0.f;
    if (BIAS) {
        float4 b4 = *(const float4*)(bias + c4);
        bx_ = b4.x; by_ = b4.y; bz_ = b4.z; bw_ = b4.w;
    }
    const int ntiles = (N + ROWS - 1) / ROWS;
    for (int tile = blockIdx.x; tile < ntiles; tile += gridDim.x) {
        const int row0 = tile * ROWS;
        __syncthreads();
        for (int i = tid; i < ROWS * KF4; i += 256) {
            int r = i / KF4, k4 = (i % KF4) * 4;
            int row = row0 + r;
            float4 v = make_float4(0.f, 0.f, 0.f, 0.f);
            if (row < N) v = *(const float4*)(x + (size_t)row * K + k4);
            *(float4*)(op + r * STRIDE + k4) = v;
        }
        __syncthreads();
        float acc[RR][4];
#pragma unroll
        for (int i = 0; i < RR; ++i) {
            float px = 0.f, py = 0.f, pz = 0.f, pw = 0.f;
            if (PRE) {
                int row = row0 + rb + i;
                if (row < N) {
                    float4 p = *(const float4*)(pre + row * 64 + c4);
                    px = p.x; py = p.y; pz = p.z; pw = p.w;
                }
            }
            acc[i][0] = bx_ + px; acc[i][1] = by_ + py;
            acc[i][2] = bz_ + pz; acc[i][3] = bw_ + pw;
        }
        for (int kk = 0; kk < K; kk += 4) {
            float4 w0 = *(const float4*)(Ws + (kk + 0) * 64 + c4);
            float4 w1 = *(const float4*)(Ws + (kk + 1) * 64 + c4);
            float4 w2 = *(const float4*)(Ws + (kk + 2) * 64 + c4);
            float4 w3 = *(const float4*)(Ws + (kk + 3) * 64 + c4);
#pragma unroll
            for (int i = 0; i < RR; ++i) {
                float4 o = *(const float4*)(op + (rb + i) * STRIDE + kk);
                FMA_ROW(acc[i], o.x, w0);
                FMA_ROW(acc[i], o.y, w1);
                FMA_ROW(acc[i], o.z, w2);
                FMA_ROW(acc[i], o.w, w3);
            }
        }
#pragma unroll
        for (int i = 0; i < RR; ++i) {
            int row = row0 + rb + i;
            if (row >= N) continue;
            float v0 = acc[i][0], v1 = acc[i][1], v2 = acc[i][2], v3 = acc[i][3];
            if (RELU) {
                v0 = fmaxf(v0, 0.f); v1 = fmaxf(v1, 0.f);
                v2 = fmaxf(v2, 0.f); v3 = fmaxf(v3, 0.f);
            }
            if (STORE)
                *(float4*)(h + row * 64 + c4) = make_float4(v0, v1, v2, v3);
            if (EMIT) {
                uint2 o;
                o.x = (u32)bf16r(v0) | ((u32)bf16r(v1) << 16);
                o.y = (u32)bf16r(v2) | ((u32)bf16r(v3) << 16);
                *(uint2*)(hbf + row * 64 + c4) = o;
            }
        }
    }
}

// ======= dual-input fused combine, STATIC LDS (K1=K2=64 only, 49 KB) =======
// h = x1@W1 + b + x2@W2 ; in-place safe for x2 == h.
__global__ __launch_bounds__(256) void k_ctile2s(const float* __restrict__ x1,
                                                 const float* __restrict__ x2,
                                                 const float* __restrict__ W1,
                                                 const float* __restrict__ W2,
                                                 const float* __restrict__ bias,
                                                 float* __restrict__ h, int N) {
    constexpr int ROWS = 32, RR = 2, S = 68;
    __shared__ float Ws1[64 * 64];
    __shared__ float Ws2[64 * 64];
    __shared__ float op1[ROWS * S];
    __shared__ float op2[ROWS * S];
    const int tid = threadIdx.x;
    for (int i = tid; i < 64 * 16; i += 256) {
        ((float4*)Ws1)[i] = ((const float4*)W1)[i];
        ((float4*)Ws2)[i] = ((const float4*)W2)[i];
    }
    const int c4 = (tid & 15) * 4;
    const int rb = (tid >> 4) * RR;
    float4 b4 = *(const float4*)(bias + c4);
    const int ntiles = (N + ROWS - 1) / ROWS;
    for (int tile = blockIdx.x; tile < ntiles; tile += gridDim.x) {
        const int row0 = tile * ROWS;
        __syncthreads();
        for (int i = tid; i < ROWS * 16; i += 256) {
            int r = i >> 4, k4 = (i & 15) * 4;
            int row = row0 + r;
            float4 v1 = make_float4(0.f, 0.f, 0.f, 0.f);
            float4 v2 = make_float4(0.f, 0.f, 0.f, 0.f);
            if (row < N) {
                v1 = *(const float4*)(x1 + (size_t)row * 64 + k4);
                v2 = *(const float4*)(x2 + (size_t)row * 64 + k4);
            }
            *(float4*)(op1 + r * S + k4) = v1;
            *(float4*)(op2 + r * S + k4) = v2;
        }
        __syncthreads();
        float acc[RR][4];
#pragma unroll
        for (int i = 0; i < RR; ++i) {
            acc[i][0] = b4.x; acc[i][1] = b4.y; acc[i][2] = b4.z; acc[i][3] = b4.w;
        }
        for (int kk = 0; kk < 64; kk += 4) {
            float4 w0 = *(const float4*)(Ws1 + (kk + 0) * 64 + c4);
            float4 w1 = *(const float4*)(Ws1 + (kk + 1) * 64 + c4);
            float4 w2 = *(const float4*)(Ws1 + (kk + 2) * 64 + c4);
            float4 w3 = *(const float4*)(Ws1 + (kk + 3) * 64 + c4);
#pragma unroll
            for (int i = 0; i < RR; ++i) {
                float4 o = *(const float4*)(op1 + (rb + i) * S + kk);
                FMA_ROW(acc[i], o.x, w0);
                FMA_ROW(acc[i], o.y, w1);
                FMA_ROW(acc[i], o.z, w2);
                FMA_ROW(acc[i], o.w, w3);
            }
        }
        for (int kk = 0; kk < 64; kk += 4) {
            float4 w0 = *(const float4*)(Ws2 + (kk + 0) * 64 + c4);
            float4 w1 = *(const float4*)(Ws2 + (kk + 1) * 64 + c4);
            float4 w2 = *(const float4*)(Ws2 + (kk + 2) * 64 + c4);
            float4 w3 = *(const float4*)(Ws2 + (kk + 3) * 64 + c4);
#pragma unroll
            for (int i = 0; i < RR; ++i) {
                float4 o = *(const float4*)(op2 + (rb + i) * S + kk);
                FMA_ROW(acc[i], o.x, w0);
                FMA_ROW(acc[i], o.y, w1);
                FMA_ROW(acc[i], o.z, w2);
                FMA_ROW(acc[i], o.w, w3);
            }
        }
#pragma unroll
        for (int i = 0; i < RR; ++i) {
            int row = row0 + rb + i;
            if (row >= N) continue;
            *(float4*)(h + row * 64 + c4) =
                make_float4(acc[i][0], acc[i][1], acc[i][2], acc[i][3]);
        }
    }
}

// ------- out[e] = dot64(hu[lu[e]], hp[lp[e]]); quarter-wave per edge, float4 -------
__global__ __launch_bounds__(256) void k_classify4(const float* __restrict__ hu,
                                                   const float* __restrict__ hp,
                                                   const int* __restrict__ lu,
                                                   const int* __restrict__ lp,
                                                   float* __restrict__ out, int EL) {
    int w = (blockIdx.x * 256 + threadIdx.x) >> 6;
    int lane = threadIdx.x & 63;
    int q = lane >> 4, t = lane & 15;
    int e = w * 4 + q;
    float v = 0.f;
    if (e < EL) {
        int u = lu[e], p = lp[e];
        float4 a = *(const float4*)(hu + u * 64 + t * 4);
        float4 b = *(const float4*)(hp + p * 64 + t * 4);
        v = a.x * b.x + a.y * b.y + a.z * b.z + a.w * b.w;
    }
#pragma unroll
    for (int m = 1; m < 16; m <<= 1) v += __shfl_xor(v, m, 64);
    if (t == 0 && e < EL) out[e] = v;
}

extern "C" void kernel_launch(void* const* d_in, const int* in_sizes, int n_in,
                              void* d_out, int out_size, void* d_ws, size_t ws_size,
                              hipStream_t stream) {
    const float* x_user    = (const float*)d_in[0];
    const float* x_product = (const float*)d_in[1];
    const float* W1bl = (const float*)d_in[2];
    const float* b1b  = (const float*)d_in[3];
    const float* W1br = (const float*)d_in[4];
    const float* W1rl = (const float*)d_in[5];
    const float* b1r  = (const float*)d_in[6];
    const float* W1rr = (const float*)d_in[7];
    const float* W2bl = (const float*)d_in[8];
    const float* b2b  = (const float*)d_in[9];
    const float* W2br = (const float*)d_in[10];
    const float* W2rl = (const float*)d_in[11];
    const float* b2r  = (const float*)d_in[12];
    const float* W2rr = (const float*)d_in[13];
    const int* esrc = (const int*)d_in[14];
    const int* edst = (const int*)d_in[15];
    const int* lu   = (const int*)d_in[16];
    const int* lp   = (const int*)d_in[17];

    const int NU = in_sizes[0] / 64;
    const int NP = in_sizes[1] / 128;
    const int E  = in_sizes[14];
    const int EL = in_sizes[16];
    const int NBP = (NP + 255) >> BSH;
    const int NBU = (NU + 255) >> BSH;

    // ---- workspace layout ----
    char* ws = (char*)d_ws;
    size_t off = 0;
    auto alloc = [&](size_t bytes) -> void* {
        void* p = ws + off;
        off += (bytes + 255) & ~(size_t)255;
        return p;
    };
    int*   deg_u  = (int*)alloc((size_t)NU * 4);
    int*   deg_p  = (int*)alloc((size_t)NP * 4);
    int*   ptr_u  = (int*)alloc((size_t)NU * 4);
    int*   ptr_p  = (int*)alloc((size_t)NP * 4);
    int*   bcntP  = (int*)alloc((size_t)MAXB * 4);   // contiguous with bcntU: one memset
    int*   bcntU  = (int*)alloc((size_t)MAXB * 4);
    int*   basesP = (int*)alloc((size_t)(MAXB + 1) * 4);
    int*   basesU = (int*)alloc((size_t)(MAXB + 1) * 4);
    int*   curP   = (int*)alloc((size_t)MAXB * 4);
    int*   curU   = (int*)alloc((size_t)MAXB * 4);
    int*   nbr_u  = (int*)alloc((size_t)E * 4);
    int*   nbr_p  = (int*)alloc((size_t)E * 4);
    // union region: pairs (CSR build) then agg (gather onward)
    size_t aggBytes = (size_t)(NP + NU) * 64 * 4;
    size_t pairBytes = (size_t)E * 8 * 2;
    char* uni = (char*)alloc(aggBytes > pairBytes ? aggBytes : pairBytes);
    float* aggP   = (float*)uni;
    float* aggU   = (float*)(uni + (size_t)NP * 64 * 4);
    uint2* pairsP = (uint2*)uni;
    uint2* pairsU = (uint2*)(uni + (size_t)E * 8);
    u16*   bfA    = (u16*)alloc((size_t)NU * 64 * 2);  // x_user_bf, then h_u_bf
    u16*   bfB    = (u16*)alloc((size_t)NP * 64 * 2);  // y_p1_bf,  then h_p_bf
    float* h_p    = (float*)alloc((size_t)NP * 64 * 4);
    float* h_u    = (float*)alloc((size_t)NU * 64 * 4);

    // ---- CSR build: bucketed counting sort, both directions ----
    hipMemsetAsync(bcntP, 0, (size_t)MAXB * 2 * 4, stream);  // bcntP+bcntU contiguous
    k_histA<<<512, 256, 0, stream>>>(esrc, edst, bcntP, bcntU, NBP, NBU, E);
    k_scanBuckets<<<2, 256, 0, stream>>>(bcntP, basesP, curP, NBP, bcntU, basesU, curU, NBU);
    const int pblocks = (E + CHUNK - 1) / CHUNK;
    k_partition<<<pblocks, 256, 0, stream>>>(edst, esrc, curP, pairsP, NBP, E);  // dir P
    k_partition<<<pblocks, 256, 0, stream>>>(esrc, edst, curU, pairsU, NBU, E);  // dir U
    k_bucketFill<<<NBP + NBU, 256, 0, stream>>>(pairsP, basesP, NBP, nbr_p, deg_p, ptr_p, NP,
                                                pairsU, basesU, NBU, nbr_u, deg_u, ptr_u, NU);

    // ---- bf16 shadows for layer-1 aggregation sources ----
    k_cast8<<<(NU * 64 / 8 + 255) / 256, 256, 0, stream>>>(x_user, bfA, NU * 64 / 8);
    // bfB = bf16(x_product @ W1rl): persistent ctile, EMIT-only (static LDS 48.5 KB)
    {
        const int tiles = (NP + 31) / 32;
        k_ctile<128, 32, false, true, false, false, false><<<(tiles < 768 ? tiles : 768), 256, 0, stream>>>(
            nullptr, nullptr, x_product, W1rl, nullptr, bfB, NP);
    }

    const int tP64 = (NP + 63) / 64, tP32 = (NP + 31) / 32;
    const int tU64 = (NU + 63) / 64, tU32 = (NU + 31) / 32;
    auto cap = [](int t, int c) { return t < c ? t : c; };

    // ---- layer 1: split per-direction gathers (L2 locality), then combines ----
    k_gather1<<<(NP + 3) / 4, 256, 0, stream>>>(bfA, nbr_p, ptr_p, deg_p, aggP, NP);
    k_gather1<<<(NU + 3) / 4, 256, 0, stream>>>(bfB, nbr_u, ptr_u, deg_u, aggU, NU);
    // h_p = relu(aggP@W1bl + b1b + x_product@W1br): two-pass (R5-proven; one-pass needs 73 KB LDS)
    k_ctile<64, 64, false, false, false, true, true><<<cap(tP64, 1024), 256, 0, stream>>>(
        nullptr, b1b, aggP, W1bl, h_p, nullptr, NP);
    k_ctile<128, 32, true, true, true, false, true><<<cap(tP32, 768), 256, 0, stream>>>(
        h_p, nullptr, x_product, W1br, h_p, bfB, NP);
    // h_u = relu(aggU + b1r + x_user@W1rr), emit bfA
    k_ctile<64, 64, true, true, true, true, true><<<cap(tU64, 1024), 256, 0, stream>>>(
        aggU, b1r, x_user, W1rr, h_u, bfA, NU);

    // ---- layer 2: split gathers, then fused static-LDS dual combines (in-place) ----
    k_gather1<<<(NP + 3) / 4, 256, 0, stream>>>(bfA, nbr_p, ptr_p, deg_p, aggP, NP);
    k_gather1<<<(NU + 3) / 4, 256, 0, stream>>>(bfB, nbr_u, ptr_u, deg_u, aggU, NU);
    k_ctile2s<<<cap(tP32, 768), 256, 0, stream>>>(aggP, h_p, W2bl, W2br, b2b, h_p, NP);
    k_ctile2s<<<cap(tU32, 768), 256, 0, stream>>>(aggU, h_u, W2rl, W2rr, b2r, h_u, NU);

    // ---- classifier ----
    k_classify4<<<((EL + 3) / 4 + 3) / 4, 256, 0, stream>>>(h_u, h_p, lu, lp, (float*)d_out, EL);
}

// Round 8
// 549.685 us; speedup vs baseline: 1.9804x; 1.9804x over previous
//
#include <hip/hip_runtime.h>

// 2-layer hetero GraphSAGE, fp32 compute, bf16 gather tables, bucketed CSR build,
// persistent-weight register-tiled combines. HARD RULE (R6/R7 post-mortems):
// one K-loop per tile kernel — dual-weight-loop kernels spill to 256 VGPR +
// half-GB scratch regardless of static/dynamic LDS. Fusion happens via the
// PRE operand (pre-accumulated addend), never via a second weight matrix.

using u16 = unsigned short;
using u32 = unsigned int;

__device__ __forceinline__ u16 bf16r(float f) {            // round-to-nearest-even
    u32 b = __float_as_uint(f);
    b += 0x7fffu + ((b >> 16) & 1u);
    return (u16)(b >> 16);
}
__device__ __forceinline__ float bflo(u32 u) { return __uint_as_float(u << 16); }
__device__ __forceinline__ float bfhi(u32 u) { return __uint_as_float(u & 0xffff0000u); }

#define BSH 8          // bucket = key >> BSH, 256 node ids per bucket
#define MAXB 512       // max buckets per direction (NU=100000 -> 391)
#define CHUNK 4096     // edges per partition block
#define RPT 16         // CHUNK / 256

// ---- pass A: coarse bucket histograms, both directions fused ----
__global__ __launch_bounds__(256) void k_histA(const int* __restrict__ esrc,
                                               const int* __restrict__ edst,
                                               int* __restrict__ bcntP,
                                               int* __restrict__ bcntU,
                                               int NBP, int NBU, int E) {
    __shared__ int hP[MAXB];
    __shared__ int hU[MAXB];
    int tid = threadIdx.x;
    for (int i = tid; i < MAXB; i += 256) { hP[i] = 0; hU[i] = 0; }
    __syncthreads();
    int E4 = E >> 2;
    const int4* s4 = (const int4*)esrc;
    const int4* d4 = (const int4*)edst;
    int stride = gridDim.x * 256;
    for (int i = blockIdx.x * 256 + tid; i < E4; i += stride) {
        int4 s = s4[i], d = d4[i];
        atomicAdd(&hU[s.x >> BSH], 1); atomicAdd(&hU[s.y >> BSH], 1);
        atomicAdd(&hU[s.z >> BSH], 1); atomicAdd(&hU[s.w >> BSH], 1);
        atomicAdd(&hP[d.x >> BSH], 1); atomicAdd(&hP[d.y >> BSH], 1);
        atomicAdd(&hP[d.z >> BSH], 1); atomicAdd(&hP[d.w >> BSH], 1);
    }
    if (blockIdx.x == 0 && tid < (E & 3)) {
        int e = E4 * 4 + tid;
        atomicAdd(&hU[esrc[e] >> BSH], 1);
        atomicAdd(&hP[edst[e] >> BSH], 1);
    }
    __syncthreads();
    for (int i = tid; i < NBP; i += 256) if (hP[i]) atomicAdd(&bcntP[i], hP[i]);
    for (int i = tid; i < NBU; i += 256) if (hU[i]) atomicAdd(&bcntU[i], hU[i]);
}

// ---- scan bucket counts -> bases[NB+1] and working cursor[NB]; block 0 = P, 1 = U ----
__global__ __launch_bounds__(256) void k_scanBuckets(const int* __restrict__ cntP,
                                                     int* __restrict__ basesP,
                                                     int* __restrict__ curP, int NBP,
                                                     const int* __restrict__ cntU,
                                                     int* __restrict__ basesU,
                                                     int* __restrict__ curU, int NBU) {
    const int* cnt; int* bases; int* cur; int NB;
    if (blockIdx.x == 0) { cnt = cntP; bases = basesP; cur = curP; NB = NBP; }
    else                 { cnt = cntU; bases = basesU; cur = curU; NB = NBU; }
    __shared__ int sA[MAXB];
    __shared__ int sB[MAXB];
    int tid = threadIdx.x;
    int v0 = (tid < NB) ? cnt[tid] : 0;
    int v1 = (tid + 256 < NB) ? cnt[tid + 256] : 0;
    sA[tid] = v0; sA[tid + 256] = v1;
    __syncthreads();
    int* src = sA; int* dst = sB;
    for (int off = 1; off < MAXB; off <<= 1) {
        dst[tid] = src[tid] + ((tid >= off) ? src[tid - off] : 0);
        int i2 = tid + 256;
        dst[i2] = src[i2] + ((i2 >= off) ? src[i2 - off] : 0);
        __syncthreads();
        int* t = src; src = dst; dst = t;
    }
    if (tid < NB)       { bases[tid] = src[tid] - v0;             cur[tid] = src[tid] - v0; }
    if (tid + 256 < NB) { bases[tid + 256] = src[tid + 256] - v1; cur[tid + 256] = src[tid + 256] - v1; }
    if (tid == 0) bases[NB] = src[MAXB - 1];
}

// ---- pass B: partition edges into bucket-ordered (key,payload) pairs, coalesced flush ----
__global__ __launch_bounds__(256) void k_partition(const int* __restrict__ keys,
                                                   const int* __restrict__ payload,
                                                   int* __restrict__ cursor,
                                                   uint2* __restrict__ pairs,
                                                   int NB, int E) {
    __shared__ int hist[MAXB];
    __shared__ int sA[MAXB];
    __shared__ int sB[MAXB];
    __shared__ int bx[MAXB];
    __shared__ int gbase[MAXB];
    __shared__ uint2 prs[CHUNK];
    int tid = threadIdx.x;
    int i0 = blockIdx.x * CHUNK;
    int count = min(CHUNK, E - i0);
    for (int i = tid; i < MAXB; i += 256) hist[i] = 0;
    __syncthreads();
    int keyr[RPT], payr[RPT], rankr[RPT];
#pragma unroll
    for (int r = 0; r < RPT; ++r) {
        int idx = r * 256 + tid;
        if (idx < count) {
            int k = keys[i0 + idx];
            keyr[r] = k;
            payr[r] = payload[i0 + idx];
            rankr[r] = atomicAdd(&hist[k >> BSH], 1);
        } else keyr[r] = -1;
    }
    __syncthreads();
    // exclusive scan of hist -> bx (ping-pong, 512 wide)
    sA[tid] = hist[tid]; sA[tid + 256] = hist[tid + 256];
    __syncthreads();
    int* src = sA; int* dst = sB;
    for (int off = 1; off < MAXB; off <<= 1) {
        dst[tid] = src[tid] + ((tid >= off) ? src[tid - off] : 0);
        int i2 = tid + 256;
        dst[i2] = src[i2] + ((i2 >= off) ? src[i2 - off] : 0);
        __syncthreads();
        int* t = src; src = dst; dst = t;
    }
    bx[tid] = src[tid] - hist[tid];
    bx[tid + 256] = src[tid + 256] - hist[tid + 256];
    __syncthreads();
    for (int b = tid; b < NB; b += 256) {
        int c = hist[b];
        gbase[b] = c ? atomicAdd(&cursor[b], c) : 0;
    }
    // stage into LDS in bucket order
#pragma unroll
    for (int r = 0; r < RPT; ++r) {
        if (keyr[r] >= 0)
            prs[bx[keyr[r] >> BSH] + rankr[r]] = make_uint2((u32)keyr[r], (u32)payr[r]);
    }
    __syncthreads();
    // coalesced segment copy-out
    for (int j = tid; j < count; j += 256) {
        uint2 pr = prs[j];
        int b = pr.x >> BSH;
        pairs[gbase[b] + (j - bx[b])] = pr;
    }
}

// ---- pass C: per-bucket fine fill -> nbr, deg, ptr(start); both directions fused ----
__global__ __launch_bounds__(256) void k_bucketFill(
    const uint2* __restrict__ pairsP, const int* __restrict__ basesP, int NBP,
    int* __restrict__ nbr_p, int* __restrict__ deg_p, int* __restrict__ ptr_p, int NP,
    const uint2* __restrict__ pairsU, const int* __restrict__ basesU, int NBU,
    int* __restrict__ nbr_u, int* __restrict__ deg_u, int* __restrict__ ptr_u, int NU) {
    const uint2* pairs; const int* bases; int* nbr; int* deg; int* ptr; int N; int bucket;
    if ((int)blockIdx.x < NBP) {
        pairs = pairsP; bases = basesP; nbr = nbr_p; deg = deg_p; ptr = ptr_p; N = NP;
        bucket = blockIdx.x;
    } else {
        pairs = pairsU; bases = basesU; nbr = nbr_u; deg = deg_u; ptr = ptr_u; N = NU;
        bucket = blockIdx.x - NBP;
    }
    int tid = threadIdx.x;
    int base = bases[bucket];
    int cnt = bases[bucket + 1] - base;
    __shared__ int h[256];
    __shared__ int s[256];
    __shared__ int cur[256];
    h[tid] = 0;
    __syncthreads();
    for (int j = tid; j < cnt; j += 256) atomicAdd(&h[pairs[base + j].x & 255], 1);
    __syncthreads();
    int d = h[tid];
    s[tid] = d;
    __syncthreads();
    for (int off = 1; off < 256; off <<= 1) {
        int v = (tid >= off) ? s[tid - off] : 0;
        __syncthreads();
        s[tid] += v;
        __syncthreads();
    }
    int excl = s[tid] - d;
    int node = bucket * 256 + tid;
    if (node < N) { deg[node] = d; ptr[node] = base + excl; }
    cur[tid] = excl;
    __syncthreads();
    for (int j = tid; j < cnt; j += 256) {
        uint2 pr = pairs[base + j];
        int pos = atomicAdd(&cur[pr.x & 255], 1);
        nbr[base + pos] = pr.y;
    }
}

// ---------------- fp32 table -> bf16 shadow, 8 elems/thread ----------------
__global__ __launch_bounds__(256) void k_cast8(const float* __restrict__ x,
                                               u16* __restrict__ y, int n8) {
    int i = blockIdx.x * 256 + threadIdx.x;
    if (i >= n8) return;
    const float4* x4 = (const float4*)x;
    float4 a = x4[i * 2], b = x4[i * 2 + 1];
    uint4 o;
    o.x = (u32)bf16r(a.x) | ((u32)bf16r(a.y) << 16);
    o.y = (u32)bf16r(a.z) | ((u32)bf16r(a.w) << 16);
    o.z = (u32)bf16r(b.x) | ((u32)bf16r(b.y) << 16);
    o.w = (u32)bf16r(b.z) | ((u32)bf16r(b.w) << 16);
    ((uint4*)y)[i] = o;
}

// ------- single-direction gather-mean; wave per node, 8 lanes per bf16 row -------
__global__ __launch_bounds__(256) void k_gather1(const u16* __restrict__ y,
                                                 const int* __restrict__ nbr,
                                                 const int* __restrict__ stp,
                                                 const int* __restrict__ degp,
                                                 float* __restrict__ agg, int N) {
    int n = (blockIdx.x * 256 + threadIdx.x) >> 6;
    int lane = threadIdx.x & 63;
    if (n >= N) return;
    const int q = lane >> 3, t = lane & 7;
    const int d = degp[n];
    int j = stp[n];
    const int end = j + d;
    float a0=0,a1=0,a2=0,a3=0,a4=0,a5=0,a6=0,a7=0;
    float b0=0,b1=0,b2=0,b3=0,b4=0,b5=0,b6=0,b7=0;
    for (; j + 16 <= end; j += 16) {
        int g0 = nbr[j + q], g1 = nbr[j + 8 + q];
        uint4 v0 = *(const uint4*)(y + g0 * 64 + t * 8);
        uint4 v1 = *(const uint4*)(y + g1 * 64 + t * 8);
        a0 += bflo(v0.x); a1 += bfhi(v0.x); a2 += bflo(v0.y); a3 += bfhi(v0.y);
        a4 += bflo(v0.z); a5 += bfhi(v0.z); a6 += bflo(v0.w); a7 += bfhi(v0.w);
        b0 += bflo(v1.x); b1 += bfhi(v1.x); b2 += bflo(v1.y); b3 += bfhi(v1.y);
        b4 += bflo(v1.z); b5 += bfhi(v1.z); b6 += bflo(v1.w); b7 += bfhi(v1.w);
    }
    for (; j + 8 <= end; j += 8) {
        int g0 = nbr[j + q];
        uint4 v0 = *(const uint4*)(y + g0 * 64 + t * 8);
        a0 += bflo(v0.x); a1 += bfhi(v0.x); a2 += bflo(v0.y); a3 += bfhi(v0.y);
        a4 += bflo(v0.z); a5 += bfhi(v0.z); a6 += bflo(v0.w); a7 += bfhi(v0.w);
    }
    if (j + q < end) {
        int g0 = nbr[j + q];
        uint4 v0 = *(const uint4*)(y + g0 * 64 + t * 8);
        a0 += bflo(v0.x); a1 += bfhi(v0.x); a2 += bflo(v0.y); a3 += bfhi(v0.y);
        a4 += bflo(v0.z); a5 += bfhi(v0.z); a6 += bflo(v0.w); a7 += bfhi(v0.w);
    }
    a0 += b0; a1 += b1; a2 += b2; a3 += b3; a4 += b4; a5 += b5; a6 += b6; a7 += b7;
#pragma unroll
    for (int m = 8; m < 64; m <<= 1) {
        a0 += __shfl_xor(a0, m, 64); a1 += __shfl_xor(a1, m, 64);
        a2 += __shfl_xor(a2, m, 64); a3 += __shfl_xor(a3, m, 64);
        a4 += __shfl_xor(a4, m, 64); a5 += __shfl_xor(a5, m, 64);
        a6 += __shfl_xor(a6, m, 64); a7 += __shfl_xor(a7, m, 64);
    }
    if (q == 0) {
        float dinv = 1.0f / (float)max(d, 1);
        float* dstp = agg + n * 64 + t * 8;
        *(float4*)dstp       = make_float4(a0 * dinv, a1 * dinv, a2 * dinv, a3 * dinv);
        *(float4*)(dstp + 4) = make_float4(a4 * dinv, a5 * dinv, a6 * dinv, a7 * dinv);
    }
}

// ======= persistent-weight register-tiled combine, single input (STATIC LDS) =======
// h = act( (PRE?pre:0) + (BIAS?b:0) + x@W );  STORE=0 -> only bf16 emit
#define FMA_ROW(ACC, O, W4) \
    ACC[0] += (O) * (W4).x; ACC[1] += (O) * (W4).y; \
    ACC[2] += (O) * (W4).z; ACC[3] += (O) * (W4).w;

template <int K, int ROWS, bool RELU, bool EMIT, bool PRE, bool BIAS, bool STORE>
__global__ __launch_bounds__(256) void k_ctile(const float* __restrict__ pre,
                                               const float* __restrict__ bias,
                                               const float* __restrict__ x,
                                               const float* __restrict__ W,
                                               float* __restrict__ h,
                                               u16* __restrict__ hbf, int N) {
    constexpr int RR = ROWS / 16;
    constexpr int STRIDE = K + 4;
    constexpr int KF4 = K / 4;
    __shared__ float Ws[K * 64];
    __shared__ float op[ROWS * STRIDE];
    const int tid = threadIdx.x;
    for (int i = tid; i < K * 16; i += 256)
        ((float4*)Ws)[i] = ((const float4*)W)[i];
    const int c4 = (tid & 15) * 4;
    const int rb = (tid >> 4) * RR;
    float bx_ = 0.f, by_ = 0.f, bz_ = 0.f, bw_ = 0.f;
    if (BIAS) {
        float4 b4 = *(const float4*)(bias + c4);
        bx_ = b4.x; by_ = b4.y; bz_ = b4.z; bw_ = b4.w;
    }
    const int ntiles = (N + ROWS - 1) / ROWS;
    for (int tile = blockIdx.x; tile < ntiles; tile += gridDim.x) {
        const int row0 = tile * ROWS;
        __syncthreads();
        for (int i = tid; i < ROWS * KF4; i += 256) {
            int r = i / KF4, k4 = (i % KF4) * 4;
            int row = row0 + r;
            float4 v = make_float4(0.f, 0.f, 0.f, 0.f);
            if (row < N) v = *(const float4*)(x + (size_t)row * K + k4);
            *(float4*)(op + r * STRIDE + k4) = v;
        }
        __syncthreads();
        float acc[RR][4];
#pragma unroll
        for (int i = 0; i < RR; ++i) {
            float px = 0.f, py = 0.f, pz = 0.f, pw = 0.f;
            if (PRE) {
                int row = row0 + rb + i;
                if (row < N) {
                    float4 p = *(const float4*)(pre + row * 64 + c4);
                    px = p.x; py = p.y; pz = p.z; pw = p.w;
                }
            }
            acc[i][0] = bx_ + px; acc[i][1] = by_ + py;
            acc[i][2] = bz_ + pz; acc[i][3] = bw_ + pw;
        }
        for (int kk = 0; kk < K; kk += 4) {
            float4 w0 = *(const float4*)(Ws + (kk + 0) * 64 + c4);
            float4 w1 = *(const float4*)(Ws + (kk + 1) * 64 + c4);
            float4 w2 = *(const float4*)(Ws + (kk + 2) * 64 + c4);
            float4 w3 = *(const float4*)(Ws + (kk + 3) * 64 + c4);
#pragma unroll
            for (int i = 0; i < RR; ++i) {
                float4 o = *(const float4*)(op + (rb + i) * STRIDE + kk);
                FMA_ROW(acc[i], o.x, w0);
                FMA_ROW(acc[i], o.y, w1);
                FMA_ROW(acc[i], o.z, w2);
                FMA_ROW(acc[i], o.w, w3);
            }
        }
#pragma unroll
        for (int i = 0; i < RR; ++i) {
            int row = row0 + rb + i;
            if (row >= N) continue;
            float v0 = acc[i][0], v1 = acc[i][1], v2 = acc[i][2], v3 = acc[i][3];
            if (RELU) {
                v0 = fmaxf(v0, 0.f); v1 = fmaxf(v1, 0.f);
                v2 = fmaxf(v2, 0.f); v3 = fmaxf(v3, 0.f);
            }
            if (STORE)
                *(float4*)(h + row * 64 + c4) = make_float4(v0, v1, v2, v3);
            if (EMIT) {
                uint2 o;
                o.x = (u32)bf16r(v0) | ((u32)bf16r(v1) << 16);
                o.y = (u32)bf16r(v2) | ((u32)bf16r(v3) << 16);
                *(uint2*)(hbf + row * 64 + c4) = o;
            }
        }
    }
}

// ------- out[e] = dot64(hu[lu[e]], hp[lp[e]]); quarter-wave per edge, float4 -------
__global__ __launch_bounds__(256) void k_classify4(const float* __restrict__ hu,
                                                   const float* __restrict__ hp,
                                                   const int* __restrict__ lu,
                                                   const int* __restrict__ lp,
                                                   float* __restrict__ out, int EL) {
    int w = (blockIdx.x * 256 + threadIdx.x) >> 6;
    int lane = threadIdx.x & 63;
    int q = lane >> 4, t = lane & 15;
    int e = w * 4 + q;
    float v = 0.f;
    if (e < EL) {
        int u = lu[e], p = lp[e];
        float4 a = *(const float4*)(hu + u * 64 + t * 4);
        float4 b = *(const float4*)(hp + p * 64 + t * 4);
        v = a.x * b.x + a.y * b.y + a.z * b.z + a.w * b.w;
    }
#pragma unroll
    for (int m = 1; m < 16; m <<= 1) v += __shfl_xor(v, m, 64);
    if (t == 0 && e < EL) out[e] = v;
}

extern "C" void kernel_launch(void* const* d_in, const int* in_sizes, int n_in,
                              void* d_out, int out_size, void* d_ws, size_t ws_size,
                              hipStream_t stream) {
    const float* x_user    = (const float*)d_in[0];
    const float* x_product = (const float*)d_in[1];
    const float* W1bl = (const float*)d_in[2];
    const float* b1b  = (const float*)d_in[3];
    const float* W1br = (const float*)d_in[4];
    const float* W1rl = (const float*)d_in[5];
    const float* b1r  = (const float*)d_in[6];
    const float* W1rr = (const float*)d_in[7];
    const float* W2bl = (const float*)d_in[8];
    const float* b2b  = (const float*)d_in[9];
    const float* W2br = (const float*)d_in[10];
    const float* W2rl = (const float*)d_in[11];
    const float* b2r  = (const float*)d_in[12];
    const float* W2rr = (const float*)d_in[13];
    const int* esrc = (const int*)d_in[14];
    const int* edst = (const int*)d_in[15];
    const int* lu   = (const int*)d_in[16];
    const int* lp   = (const int*)d_in[17];

    const int NU = in_sizes[0] / 64;
    const int NP = in_sizes[1] / 128;
    const int E  = in_sizes[14];
    const int EL = in_sizes[16];
    const int NBP = (NP + 255) >> BSH;
    const int NBU = (NU + 255) >> BSH;

    // ---- workspace layout ----
    char* ws = (char*)d_ws;
    size_t off = 0;
    auto alloc = [&](size_t bytes) -> void* {
        void* p = ws + off;
        off += (bytes + 255) & ~(size_t)255;
        return p;
    };
    int*   deg_u  = (int*)alloc((size_t)NU * 4);
    int*   deg_p  = (int*)alloc((size_t)NP * 4);
    int*   ptr_u  = (int*)alloc((size_t)NU * 4);
    int*   ptr_p  = (int*)alloc((size_t)NP * 4);
    int*   bcntP  = (int*)alloc((size_t)MAXB * 4);   // contiguous with bcntU: one memset
    int*   bcntU  = (int*)alloc((size_t)MAXB * 4);
    int*   basesP = (int*)alloc((size_t)(MAXB + 1) * 4);
    int*   basesU = (int*)alloc((size_t)(MAXB + 1) * 4);
    int*   curP   = (int*)alloc((size_t)MAXB * 4);
    int*   curU   = (int*)alloc((size_t)MAXB * 4);
    int*   nbr_u  = (int*)alloc((size_t)E * 4);
    int*   nbr_p  = (int*)alloc((size_t)E * 4);
    // union region: pairs (CSR build) then agg (gather onward)
    size_t aggBytes = (size_t)(NP + NU) * 64 * 4;
    size_t pairBytes = (size_t)E * 8 * 2;
    char* uni = (char*)alloc(aggBytes > pairBytes ? aggBytes : pairBytes);
    float* aggP   = (float*)uni;
    float* aggU   = (float*)(uni + (size_t)NP * 64 * 4);
    uint2* pairsP = (uint2*)uni;
    uint2* pairsU = (uint2*)(uni + (size_t)E * 8);
    u16*   bfA    = (u16*)alloc((size_t)NU * 64 * 2);  // x_user_bf, then h_u_bf
    u16*   bfB    = (u16*)alloc((size_t)NP * 64 * 2);  // y_p1_bf,  then h_p_bf
    float* h_p    = (float*)alloc((size_t)NP * 64 * 4);
    float* h_u    = (float*)alloc((size_t)NU * 64 * 4);

    // ---- CSR build: bucketed counting sort, both directions ----
    hipMemsetAsync(bcntP, 0, (size_t)MAXB * 2 * 4, stream);  // bcntP+bcntU contiguous
    k_histA<<<512, 256, 0, stream>>>(esrc, edst, bcntP, bcntU, NBP, NBU, E);
    k_scanBuckets<<<2, 256, 0, stream>>>(bcntP, basesP, curP, NBP, bcntU, basesU, curU, NBU);
    const int pblocks = (E + CHUNK - 1) / CHUNK;
    k_partition<<<pblocks, 256, 0, stream>>>(edst, esrc, curP, pairsP, NBP, E);  // dir P
    k_partition<<<pblocks, 256, 0, stream>>>(esrc, edst, curU, pairsU, NBU, E);  // dir U
    k_bucketFill<<<NBP + NBU, 256, 0, stream>>>(pairsP, basesP, NBP, nbr_p, deg_p, ptr_p, NP,
                                                pairsU, basesU, NBU, nbr_u, deg_u, ptr_u, NU);

    // ---- bf16 shadows for layer-1 aggregation sources ----
    k_cast8<<<(NU * 64 / 8 + 255) / 256, 256, 0, stream>>>(x_user, bfA, NU * 64 / 8);
    // bfB = bf16(x_product @ W1rl): persistent ctile, EMIT-only (static LDS 48.5 KB)
    {
        const int tiles = (NP + 31) / 32;
        k_ctile<128, 32, false, true, false, false, false><<<(tiles < 768 ? tiles : 768), 256, 0, stream>>>(
            nullptr, nullptr, x_product, W1rl, nullptr, bfB, NP);
    }

    const int tP64 = (NP + 63) / 64, tP32 = (NP + 31) / 32;
    const int tU64 = (NU + 63) / 64;
    auto cap = [](int t, int c) { return t < c ? t : c; };

    // ---- layer 1: split per-direction gathers (L2 locality), then combines ----
    k_gather1<<<(NP + 3) / 4, 256, 0, stream>>>(bfA, nbr_p, ptr_p, deg_p, aggP, NP);
    k_gather1<<<(NU + 3) / 4, 256, 0, stream>>>(bfB, nbr_u, ptr_u, deg_u, aggU, NU);
    // h_p = relu(aggP@W1bl + b1b + x_product@W1br): two-pass (R5-proven shape)
    k_ctile<64, 64, false, false, false, true, true><<<cap(tP64, 1024), 256, 0, stream>>>(
        nullptr, b1b, aggP, W1bl, h_p, nullptr, NP);
    k_ctile<128, 32, true, true, true, false, true><<<cap(tP32, 768), 256, 0, stream>>>(
        h_p, nullptr, x_product, W1br, h_p, bfB, NP);
    // h_u = relu(aggU + b1r + x_user@W1rr), emit bfA
    k_ctile<64, 64, true, true, true, true, true><<<cap(tU64, 1024), 256, 0, stream>>>(
        aggU, b1r, x_user, W1rr, h_u, bfA, NU);

    // ---- layer 2: split gathers, then R5-proven 4-dispatch single-K chain ----
    k_gather1<<<(NP + 3) / 4, 256, 0, stream>>>(bfA, nbr_p, ptr_p, deg_p, aggP, NP);
    k_gather1<<<(NU + 3) / 4, 256, 0, stream>>>(bfB, nbr_u, ptr_u, deg_u, aggU, NU);
    k_ctile<64, 64, false, false, false, true, true><<<cap(tP64, 1024), 256, 0, stream>>>(
        nullptr, b2b, aggP, W2bl, aggP, nullptr, NP);          // aggP = aggP@W2bl + b2b
    k_ctile<64, 64, false, false, false, true, true><<<cap(tU64, 1024), 256, 0, stream>>>(
        nullptr, b2r, aggU, W2rl, aggU, nullptr, NU);          // aggU = aggU@W2rl + b2r
    k_ctile<64, 64, false, false, true, false, true><<<cap(tP64, 1024), 256, 0, stream>>>(
        aggP, nullptr, h_p, W2br, h_p, nullptr, NP);           // h_p = aggP + h_p@W2br
    k_ctile<64, 64, false, false, true, false, true><<<cap(tU64, 1024), 256, 0, stream>>>(
        aggU, nullptr, h_u, W2rr, h_u, nullptr, NU);           // h_u = aggU + h_u@W2rr

    // ---- classifier ----
    k_classify4<<<((EL + 3) / 4 + 3) / 4, 256, 0, stream>>>(h_u, h_p, lu, lp, (float*)d_out, EL);
}

// Round 9
// 548.710 us; speedup vs baseline: 1.9839x; 1.0018x over previous
//
#include <hip/hip_runtime.h>

// 2-layer hetero GraphSAGE, fp32 compute, bf16 gather tables, bucketed CSR build,
// persistent-weight register-tiled combines. HARD RULE (R6/R7 post-mortems):
// one K-loop per tile kernel — dual-weight-loop kernels spill to 256 VGPR +
// half-GB scratch regardless of static/dynamic LDS. Fusion happens via the
// PRE operand or block-range parameter selection (k_ctilePair64), never via a
// second weight matrix in the same loop nest. R8 post-mortem: split gathers
// lower FETCH but not time (latency-bound) — keep the fused dual gather.

using u16 = unsigned short;
using u32 = unsigned int;

__device__ __forceinline__ u16 bf16r(float f) {            // round-to-nearest-even
    u32 b = __float_as_uint(f);
    b += 0x7fffu + ((b >> 16) & 1u);
    return (u16)(b >> 16);
}
__device__ __forceinline__ float bflo(u32 u) { return __uint_as_float(u << 16); }
__device__ __forceinline__ float bfhi(u32 u) { return __uint_as_float(u & 0xffff0000u); }

#define BSH 8          // bucket = key >> BSH, 256 node ids per bucket
#define MAXB 512       // max buckets per direction (NU=100000 -> 391)
#define CHUNK 4096     // edges per partition block
#define RPT 16         // CHUNK / 256

// ---- pass A: coarse bucket histograms, both directions fused ----
__global__ __launch_bounds__(256) void k_histA(const int* __restrict__ esrc,
                                               const int* __restrict__ edst,
                                               int* __restrict__ bcntP,
                                               int* __restrict__ bcntU,
                                               int NBP, int NBU, int E) {
    __shared__ int hP[MAXB];
    __shared__ int hU[MAXB];
    int tid = threadIdx.x;
    for (int i = tid; i < MAXB; i += 256) { hP[i] = 0; hU[i] = 0; }
    __syncthreads();
    int E4 = E >> 2;
    const int4* s4 = (const int4*)esrc;
    const int4* d4 = (const int4*)edst;
    int stride = gridDim.x * 256;
    for (int i = blockIdx.x * 256 + tid; i < E4; i += stride) {
        int4 s = s4[i], d = d4[i];
        atomicAdd(&hU[s.x >> BSH], 1); atomicAdd(&hU[s.y >> BSH], 1);
        atomicAdd(&hU[s.z >> BSH], 1); atomicAdd(&hU[s.w >> BSH], 1);
        atomicAdd(&hP[d.x >> BSH], 1); atomicAdd(&hP[d.y >> BSH], 1);
        atomicAdd(&hP[d.z >> BSH], 1); atomicAdd(&hP[d.w >> BSH], 1);
    }
    if (blockIdx.x == 0 && tid < (E & 3)) {
        int e = E4 * 4 + tid;
        atomicAdd(&hU[esrc[e] >> BSH], 1);
        atomicAdd(&hP[edst[e] >> BSH], 1);
    }
    __syncthreads();
    for (int i = tid; i < NBP; i += 256) if (hP[i]) atomicAdd(&bcntP[i], hP[i]);
    for (int i = tid; i < NBU; i += 256) if (hU[i]) atomicAdd(&bcntU[i], hU[i]);
}

// ---- scan bucket counts -> bases[NB+1] and working cursor[NB]; block 0 = P, 1 = U ----
__global__ __launch_bounds__(256) void k_scanBuckets(const int* __restrict__ cntP,
                                                     int* __restrict__ basesP,
                                                     int* __restrict__ curP, int NBP,
                                                     const int* __restrict__ cntU,
                                                     int* __restrict__ basesU,
                                                     int* __restrict__ curU, int NBU) {
    const int* cnt; int* bases; int* cur; int NB;
    if (blockIdx.x == 0) { cnt = cntP; bases = basesP; cur = curP; NB = NBP; }
    else                 { cnt = cntU; bases = basesU; cur = curU; NB = NBU; }
    __shared__ int sA[MAXB];
    __shared__ int sB[MAXB];
    int tid = threadIdx.x;
    int v0 = (tid < NB) ? cnt[tid] : 0;
    int v1 = (tid + 256 < NB) ? cnt[tid + 256] : 0;
    sA[tid] = v0; sA[tid + 256] = v1;
    __syncthreads();
    int* src = sA; int* dst = sB;
    for (int off = 1; off < MAXB; off <<= 1) {
        dst[tid] = src[tid] + ((tid >= off) ? src[tid - off] : 0);
        int i2 = tid + 256;
        dst[i2] = src[i2] + ((i2 >= off) ? src[i2 - off] : 0);
        __syncthreads();
        int* t = src; src = dst; dst = t;
    }
    if (tid < NB)       { bases[tid] = src[tid] - v0;             cur[tid] = src[tid] - v0; }
    if (tid + 256 < NB) { bases[tid + 256] = src[tid + 256] - v1; cur[tid + 256] = src[tid + 256] - v1; }
    if (tid == 0) bases[NB] = src[MAXB - 1];
}

// ---- pass B: partition edges into bucket-ordered (key,payload) pairs, coalesced flush ----
__global__ __launch_bounds__(256) void k_partition(const int* __restrict__ keys,
                                                   const int* __restrict__ payload,
                                                   int* __restrict__ cursor,
                                                   uint2* __restrict__ pairs,
                                                   int NB, int E) {
    __shared__ int hist[MAXB];
    __shared__ int sA[MAXB];
    __shared__ int sB[MAXB];
    __shared__ int bx[MAXB];
    __shared__ int gbase[MAXB];
    __shared__ uint2 prs[CHUNK];
    int tid = threadIdx.x;
    int i0 = blockIdx.x * CHUNK;
    int count = min(CHUNK, E - i0);
    for (int i = tid; i < MAXB; i += 256) hist[i] = 0;
    __syncthreads();
    int keyr[RPT], payr[RPT], rankr[RPT];
#pragma unroll
    for (int r = 0; r < RPT; ++r) {
        int idx = r * 256 + tid;
        if (idx < count) {
            int k = keys[i0 + idx];
            keyr[r] = k;
            payr[r] = payload[i0 + idx];
            rankr[r] = atomicAdd(&hist[k >> BSH], 1);
        } else keyr[r] = -1;
    }
    __syncthreads();
    // exclusive scan of hist -> bx (ping-pong, 512 wide)
    sA[tid] = hist[tid]; sA[tid + 256] = hist[tid + 256];
    __syncthreads();
    int* src = sA; int* dst = sB;
    for (int off = 1; off < MAXB; off <<= 1) {
        dst[tid] = src[tid] + ((tid >= off) ? src[tid - off] : 0);
        int i2 = tid + 256;
        dst[i2] = src[i2] + ((i2 >= off) ? src[i2 - off] : 0);
        __syncthreads();
        int* t = src; src = dst; dst = t;
    }
    bx[tid] = src[tid] - hist[tid];
    bx[tid + 256] = src[tid + 256] - hist[tid + 256];
    __syncthreads();
    for (int b = tid; b < NB; b += 256) {
        int c = hist[b];
        gbase[b] = c ? atomicAdd(&cursor[b], c) : 0;
    }
    // stage into LDS in bucket order
#pragma unroll
    for (int r = 0; r < RPT; ++r) {
        if (keyr[r] >= 0)
            prs[bx[keyr[r] >> BSH] + rankr[r]] = make_uint2((u32)keyr[r], (u32)payr[r]);
    }
    __syncthreads();
    // coalesced segment copy-out
    for (int j = tid; j < count; j += 256) {
        uint2 pr = prs[j];
        int b = pr.x >> BSH;
        pairs[gbase[b] + (j - bx[b])] = pr;
    }
}

// ---- pass C: per-bucket fine fill -> nbr, deg, ptr(start); both directions fused ----
__global__ __launch_bounds__(256) void k_bucketFill(
    const uint2* __restrict__ pairsP, const int* __restrict__ basesP, int NBP,
    int* __restrict__ nbr_p, int* __restrict__ deg_p, int* __restrict__ ptr_p, int NP,
    const uint2* __restrict__ pairsU, const int* __restrict__ basesU, int NBU,
    int* __restrict__ nbr_u, int* __restrict__ deg_u, int* __restrict__ ptr_u, int NU) {
    const uint2* pairs; const int* bases; int* nbr; int* deg; int* ptr; int N; int bucket;
    if ((int)blockIdx.x < NBP) {
        pairs = pairsP; bases = basesP; nbr = nbr_p; deg = deg_p; ptr = ptr_p; N = NP;
        bucket = blockIdx.x;
    } else {
        pairs = pairsU; bases = basesU; nbr = nbr_u; deg = deg_u; ptr = ptr_u; N = NU;
        bucket = blockIdx.x - NBP;
    }
    int tid = threadIdx.x;
    int base = bases[bucket];
    int cnt = bases[bucket + 1] - base;
    __shared__ int h[256];
    __shared__ int s[256];
    __shared__ int cur[256];
    h[tid] = 0;
    __syncthreads();
    for (int j = tid; j < cnt; j += 256) atomicAdd(&h[pairs[base + j].x & 255], 1);
    __syncthreads();
    int d = h[tid];
    s[tid] = d;
    __syncthreads();
    for (int off = 1; off < 256; off <<= 1) {
        int v = (tid >= off) ? s[tid - off] : 0;
        __syncthreads();
        s[tid] += v;
        __syncthreads();
    }
    int excl = s[tid] - d;
    int node = bucket * 256 + tid;
    if (node < N) { deg[node] = d; ptr[node] = base + excl; }
    cur[tid] = excl;
    __syncthreads();
    for (int j = tid; j < cnt; j += 256) {
        uint2 pr = pairs[base + j];
        int pos = atomicAdd(&cur[pr.x & 255], 1);
        nbr[base + pos] = pr.y;
    }
}

// ---------------- fp32 table -> bf16 shadow, 8 elems/thread ----------------
__global__ __launch_bounds__(256) void k_cast8(const float* __restrict__ x,
                                               u16* __restrict__ y, int n8) {
    int i = blockIdx.x * 256 + threadIdx.x;
    if (i >= n8) return;
    const float4* x4 = (const float4*)x;
    float4 a = x4[i * 2], b = x4[i * 2 + 1];
    uint4 o;
    o.x = (u32)bf16r(a.x) | ((u32)bf16r(a.y) << 16);
    o.y = (u32)bf16r(a.z) | ((u32)bf16r(a.w) << 16);
    o.z = (u32)bf16r(b.x) | ((u32)bf16r(b.y) << 16);
    o.w = (u32)bf16r(b.z) | ((u32)bf16r(b.w) << 16);
    ((uint4*)y)[i] = o;
}

#define ACC8(A0,A1,A2,A3,A4,A5,A6,A7,V) \
    A0 += bflo((V).x); A1 += bfhi((V).x); A2 += bflo((V).y); A3 += bfhi((V).y); \
    A4 += bflo((V).z); A5 += bfhi((V).z); A6 += bflo((V).w); A7 += bfhi((V).w);

// ------- fused dual gather-mean: nodes [0,NA) CSR A, [NA,NA+NB) CSR B -------
// wave per node; 8 lanes per bf16 row (uint4); 32 neighbors in flight per iter
__global__ __launch_bounds__(256) void k_gather2(
    const u16* __restrict__ yA, const int* __restrict__ nbrA, const int* __restrict__ stpA,
    const int* __restrict__ degA, float* __restrict__ aggA, int NA,
    const u16* __restrict__ yB, const int* __restrict__ nbrB, const int* __restrict__ stpB,
    const int* __restrict__ degB, float* __restrict__ aggB, int NB) {
    int w = (blockIdx.x * 256 + threadIdx.x) >> 6;
    int lane = threadIdx.x & 63;
    if (w >= NA + NB) return;
    const u16* y; const int* nbr; const int* stp; const int* deg; float* agg; int n;
    if (w < NA) { y = yA; nbr = nbrA; stp = stpA; deg = degA; agg = aggA; n = w; }
    else        { y = yB; nbr = nbrB; stp = stpB; deg = degB; agg = aggB; n = w - NA; }
    const int q = lane >> 3, t = lane & 7;
    const int d = deg[n];
    int j = stp[n];
    const int end = j + d;
    float a0=0,a1=0,a2=0,a3=0,a4=0,a5=0,a6=0,a7=0;
    float b0=0,b1=0,b2=0,b3=0,b4=0,b5=0,b6=0,b7=0;
    float c0=0,c1=0,c2=0,c3=0,c4=0,c5=0,c6=0,c7=0;
    float e0=0,e1=0,e2=0,e3=0,e4=0,e5=0,e6=0,e7=0;
    for (; j + 32 <= end; j += 32) {
        int g0 = nbr[j + q], g1 = nbr[j + 8 + q], g2 = nbr[j + 16 + q], g3 = nbr[j + 24 + q];
        uint4 v0 = *(const uint4*)(y + g0 * 64 + t * 8);
        uint4 v1 = *(const uint4*)(y + g1 * 64 + t * 8);
        uint4 v2 = *(const uint4*)(y + g2 * 64 + t * 8);
        uint4 v3 = *(const uint4*)(y + g3 * 64 + t * 8);
        ACC8(a0,a1,a2,a3,a4,a5,a6,a7,v0);
        ACC8(b0,b1,b2,b3,b4,b5,b6,b7,v1);
        ACC8(c0,c1,c2,c3,c4,c5,c6,c7,v2);
        ACC8(e0,e1,e2,e3,e4,e5,e6,e7,v3);
    }
    for (; j + 16 <= end; j += 16) {
        int g0 = nbr[j + q], g1 = nbr[j + 8 + q];
        uint4 v0 = *(const uint4*)(y + g0 * 64 + t * 8);
        uint4 v1 = *(const uint4*)(y + g1 * 64 + t * 8);
        ACC8(a0,a1,a2,a3,a4,a5,a6,a7,v0);
        ACC8(b0,b1,b2,b3,b4,b5,b6,b7,v1);
    }
    for (; j + 8 <= end; j += 8) {
        int g0 = nbr[j + q];
        uint4 v0 = *(const uint4*)(y + g0 * 64 + t * 8);
        ACC8(a0,a1,a2,a3,a4,a5,a6,a7,v0);
    }
    if (j + q < end) {
        int g0 = nbr[j + q];
        uint4 v0 = *(const uint4*)(y + g0 * 64 + t * 8);
        ACC8(a0,a1,a2,a3,a4,a5,a6,a7,v0);
    }
    a0 += b0 + c0 + e0; a1 += b1 + c1 + e1; a2 += b2 + c2 + e2; a3 += b3 + c3 + e3;
    a4 += b4 + c4 + e4; a5 += b5 + c5 + e5; a6 += b6 + c6 + e6; a7 += b7 + c7 + e7;
#pragma unroll
    for (int m = 8; m < 64; m <<= 1) {
        a0 += __shfl_xor(a0, m, 64); a1 += __shfl_xor(a1, m, 64);
        a2 += __shfl_xor(a2, m, 64); a3 += __shfl_xor(a3, m, 64);
        a4 += __shfl_xor(a4, m, 64); a5 += __shfl_xor(a5, m, 64);
        a6 += __shfl_xor(a6, m, 64); a7 += __shfl_xor(a7, m, 64);
    }
    if (q == 0) {
        float dinv = 1.0f / (float)max(d, 1);
        float* dstp = agg + n * 64 + t * 8;
        *(float4*)dstp       = make_float4(a0 * dinv, a1 * dinv, a2 * dinv, a3 * dinv);
        *(float4*)(dstp + 4) = make_float4(a4 * dinv, a5 * dinv, a6 * dinv, a7 * dinv);
    }
}

// ======= persistent-weight register-tiled combine, single input (STATIC LDS) =======
// h = act( (PRE?pre:0) + (BIAS?b:0) + x@W );  STORE=0 -> only bf16 emit
#define FMA_ROW(ACC, O, W4) \
    ACC[0] += (O) * (W4).x; ACC[1] += (O) * (W4).y; \
    ACC[2] += (O) * (W4).z; ACC[3] += (O) * (W4).w;

template <int K, int ROWS, bool RELU, bool EMIT, bool PRE, bool BIAS, bool STORE>
__global__ __launch_bounds__(256) void k_ctile(const float* __restrict__ pre,
                                               const float* __restrict__ bias,
                                               const float* __restrict__ x,
                                               const float* __restrict__ W,
                                               float* __restrict__ h,
                                               u16* __restrict__ hbf, int N) {
    constexpr int RR = ROWS / 16;
    constexpr int STRIDE = K + 4;
    constexpr int KF4 = K / 4;
    __shared__ float Ws[K * 64];
    __shared__ float op[ROWS * STRIDE];
    const int tid = threadIdx.x;
    for (int i = tid; i < K * 16; i += 256)
        ((float4*)Ws)[i] = ((const float4*)W)[i];
    const int c4 = (tid & 15) * 4;
    const int rb = (tid >> 4) * RR;
    float bx_ = 0.f, by_ = 0.f, bz_ = 0.f, bw_ = 0.f;
    if (BIAS) {
        float4 b4 = *(const float4*)(bias + c4);
        bx_ = b4.x; by_ = b4.y; bz_ = b4.z; bw_ = b4.w;
    }
    const int ntiles = (N + ROWS - 1) / ROWS;
    for (int tile = blockIdx.x; tile < ntiles; tile += gridDim.x) {
        const int row0 = tile * ROWS;
        __syncthreads();
        for (int i = tid; i < ROWS * KF4; i += 256) {
            int r = i / KF4, k4 = (i % KF4) * 4;
            int row = row0 + r;
            float4 v = make_float4(0.f, 0.f, 0.f, 0.f);
            if (row < N) v = *(const float4*)(x + (size_t)row * K + k4);
            *(float4*)(op + r * STRIDE + k4) = v;
        }
        __syncthreads();
        float acc[RR][4];
#pragma unroll
        for (int i = 0; i < RR; ++i) {
            float px = 0.f, py = 0.f, pz = 0.f, pw = 0.f;
            if (PRE) {
                int row = row0 + rb + i;
                if (row < N) {
                    float4 p = *(const float4*)(pre + row * 64 + c4);
                    px = p.x; py = p.y; pz = p.z; pw = p.w;
                }
            }
            acc[i][0] = bx_ + px; acc[i][1] = by_ + py;
            acc[i][2] = bz_ + pz; acc[i][3] = bw_ + pw;
        }
        for (int kk = 0; kk < K; kk += 4) {
            float4 w0 = *(const float4*)(Ws + (kk + 0) * 64 + c4);
            float4 w1 = *(const float4*)(Ws + (kk + 1) * 64 + c4);
            float4 w2 = *(const float4*)(Ws + (kk + 2) * 64 + c4);
            float4 w3 = *(const float4*)(Ws + (kk + 3) * 64 + c4);
#pragma unroll
            for (int i = 0; i < RR; ++i) {
                float4 o = *(const float4*)(op + (rb + i) * STRIDE + kk);
                FMA_ROW(acc[i], o.x, w0);
                FMA_ROW(acc[i], o.y, w1);
                FMA_ROW(acc[i], o.z, w2);
                FMA_ROW(acc[i], o.w, w3);
            }
        }
#pragma unroll
        for (int i = 0; i < RR; ++i) {
            int row = row0 + rb + i;
            if (row >= N) continue;
            float v0 = acc[i][0], v1 = acc[i][1], v2 = acc[i][2], v3 = acc[i][3];
            if (RELU) {
                v0 = fmaxf(v0, 0.f); v1 = fmaxf(v1, 0.f);
                v2 = fmaxf(v2, 0.f); v3 = fmaxf(v3, 0.f);
            }
            if (STORE)
                *(float4*)(h + row * 64 + c4) = make_float4(v0, v1, v2, v3);
            if (EMIT) {
                uint2 o;
                o.x = (u32)bf16r(v0) | ((u32)bf16r(v1) << 16);
                o.y = (u32)bf16r(v2) | ((u32)bf16r(v3) << 16);
                *(uint2*)(hbf + row * 64 + c4) = o;
            }
        }
    }
}

// ======= paired combine: two independent K=64 problems, block-range selected =======
// Each block picks ONE (pre,bias,x,W,h,N) set and runs the standard single-K-loop
// body — no dual-weight spill hazard. h = (PRE?pre:0) + (BIAS?b:0) + x@W.
template <bool PRE, bool BIAS>
__global__ __launch_bounds__(256) void k_ctilePair64(
    const float* __restrict__ pre0, const float* __restrict__ bias0,
    const float* __restrict__ x0, const float* __restrict__ W0,
    float* __restrict__ h0, int N0, int g0,
    const float* __restrict__ pre1, const float* __restrict__ bias1,
    const float* __restrict__ x1, const float* __restrict__ W1,
    float* __restrict__ h1, int N1) {
    constexpr int ROWS = 64, RR = 4, STRIDE = 68, KF4 = 16;
    __shared__ float Ws[64 * 64];
    __shared__ float op[ROWS * STRIDE];
    const float* pre; const float* bias; const float* x; const float* W; float* h;
    int N, bid, gsz;
    if ((int)blockIdx.x < g0) {
        pre = pre0; bias = bias0; x = x0; W = W0; h = h0; N = N0;
        bid = blockIdx.x; gsz = g0;
    } else {
        pre = pre1; bias = bias1; x = x1; W = W1; h = h1; N = N1;
        bid = blockIdx.x - g0; gsz = gridDim.x - g0;
    }
    const int tid = threadIdx.x;
    for (int i = tid; i < 64 * 16; i += 256)
        ((float4*)Ws)[i] = ((const float4*)W)[i];
    const int c4 = (tid & 15) * 4;
    const int rb = (tid >> 4) * RR;
    float bx_ = 0.f, by_ = 0.f, bz_ = 0.f, bw_ = 0.f;
    if (BIAS) {
        float4 b4 = *(const float4*)(bias + c4);
        bx_ = b4.x; by_ = b4.y; bz_ = b4.z; bw_ = b4.w;
    }
    const int ntiles = (N + ROWS - 1) / ROWS;
    for (int tile = bid; tile < ntiles; tile += gsz) {
        const int row0 = tile * ROWS;
        __syncthreads();
        for (int i = tid; i < ROWS * KF4; i += 256) {
            int r = i / KF4, k4 = (i % KF4) * 4;
            int row = row0 + r;
            float4 v = make_float4(0.f, 0.f, 0.f, 0.f);
            if (row < N) v = *(const float4*)(x + (size_t)row * 64 + k4);
            *(float4*)(op + r * STRIDE + k4) = v;
        }
        __syncthreads();
        float acc[RR][4];
#pragma unroll
        for (int i = 0; i < RR; ++i) {
            float px = 0.f, py = 0.f, pz = 0.f, pw = 0.f;
            if (PRE) {
                int row = row0 + rb + i;
                if (row < N) {
                    float4 p = *(const float4*)(pre + row * 64 + c4);
                    px = p.x; py = p.y; pz = p.z; pw = p.w;
                }
            }
            acc[i][0] = bx_ + px; acc[i][1] = by_ + py;
            acc[i][2] = bz_ + pz; acc[i][3] = bw_ + pw;
        }
        for (int kk = 0; kk < 64; kk += 4) {
            float4 w0 = *(const float4*)(Ws + (kk + 0) * 64 + c4);
            float4 w1 = *(const float4*)(Ws + (kk + 1) * 64 + c4);
            float4 w2 = *(const float4*)(Ws + (kk + 2) * 64 + c4);
            float4 w3 = *(const float4*)(Ws + (kk + 3) * 64 + c4);
#pragma unroll
            for (int i = 0; i < RR; ++i) {
                float4 o = *(const float4*)(op + (rb + i) * STRIDE + kk);
                FMA_ROW(acc[i], o.x, w0);
                FMA_ROW(acc[i], o.y, w1);
                FMA_ROW(acc[i], o.z, w2);
                FMA_ROW(acc[i], o.w, w3);
            }
        }
#pragma unroll
        for (int i = 0; i < RR; ++i) {
            int row = row0 + rb + i;
            if (row >= N) continue;
            *(float4*)(h + row * 64 + c4) =
                make_float4(acc[i][0], acc[i][1], acc[i][2], acc[i][3]);
        }
    }
}

// ------- out[e] = dot64(hu[lu[e]], hp[lp[e]]); quarter-wave per edge, float4 -------
__global__ __launch_bounds__(256) void k_classify4(const float* __restrict__ hu,
                                                   const float* __restrict__ hp,
                                                   const int* __restrict__ lu,
                                                   const int* __restrict__ lp,
                                                   float* __restrict__ out, int EL) {
    int w = (blockIdx.x * 256 + threadIdx.x) >> 6;
    int lane = threadIdx.x & 63;
    int q = lane >> 4, t = lane & 15;
    int e = w * 4 + q;
    float v = 0.f;
    if (e < EL) {
        int u = lu[e], p = lp[e];
        float4 a = *(const float4*)(hu + u * 64 + t * 4);
        float4 b = *(const float4*)(hp + p * 64 + t * 4);
        v = a.x * b.x + a.y * b.y + a.z * b.z + a.w * b.w;
    }
#pragma unroll
    for (int m = 1; m < 16; m <<= 1) v += __shfl_xor(v, m, 64);
    if (t == 0 && e < EL) out[e] = v;
}

extern "C" void kernel_launch(void* const* d_in, const int* in_sizes, int n_in,
                              void* d_out, int out_size, void* d_ws, size_t ws_size,
                              hipStream_t stream) {
    const float* x_user    = (const float*)d_in[0];
    const float* x_product = (const float*)d_in[1];
    const float* W1bl = (const float*)d_in[2];
    const float* b1b  = (const float*)d_in[3];
    const float* W1br = (const float*)d_in[4];
    const float* W1rl = (const float*)d_in[5];
    const float* b1r  = (const float*)d_in[6];
    const float* W1rr = (const float*)d_in[7];
    const float* W2bl = (const float*)d_in[8];
    const float* b2b  = (const float*)d_in[9];
    const float* W2br = (const float*)d_in[10];
    const float* W2rl = (const float*)d_in[11];
    const float* b2r  = (const float*)d_in[12];
    const float* W2rr = (const float*)d_in[13];
    const int* esrc = (const int*)d_in[14];
    const int* edst = (const int*)d_in[15];
    const int* lu   = (const int*)d_in[16];
    const int* lp   = (const int*)d_in[17];

    const int NU = in_sizes[0] / 64;
    const int NP = in_sizes[1] / 128;
    const int E  = in_sizes[14];
    const int EL = in_sizes[16];
    const int NBP = (NP + 255) >> BSH;
    const int NBU = (NU + 255) >> BSH;

    // ---- workspace layout ----
    char* ws = (char*)d_ws;
    size_t off = 0;
    auto alloc = [&](size_t bytes) -> void* {
        void* p = ws + off;
        off += (bytes + 255) & ~(size_t)255;
        return p;
    };
    int*   deg_u  = (int*)alloc((size_t)NU * 4);
    int*   deg_p  = (int*)alloc((size_t)NP * 4);
    int*   ptr_u  = (int*)alloc((size_t)NU * 4);
    int*   ptr_p  = (int*)alloc((size_t)NP * 4);
    int*   bcntP  = (int*)alloc((size_t)MAXB * 4);   // contiguous with bcntU: one memset
    int*   bcntU  = (int*)alloc((size_t)MAXB * 4);
    int*   basesP = (int*)alloc((size_t)(MAXB + 1) * 4);
    int*   basesU = (int*)alloc((size_t)(MAXB + 1) * 4);
    int*   curP   = (int*)alloc((size_t)MAXB * 4);
    int*   curU   = (int*)alloc((size_t)MAXB * 4);
    int*   nbr_u  = (int*)alloc((size_t)E * 4);
    int*   nbr_p  = (int*)alloc((size_t)E * 4);
    // union region: pairs (CSR build) then agg (gather onward)
    size_t aggBytes = (size_t)(NP + NU) * 64 * 4;
    size_t pairBytes = (size_t)E * 8 * 2;
    char* uni = (char*)alloc(aggBytes > pairBytes ? aggBytes : pairBytes);
    float* aggP   = (float*)uni;
    float* aggU   = (float*)(uni + (size_t)NP * 64 * 4);
    uint2* pairsP = (uint2*)uni;
    uint2* pairsU = (uint2*)(uni + (size_t)E * 8);
    u16*   bfA    = (u16*)alloc((size_t)NU * 64 * 2);  // x_user_bf, then h_u_bf
    u16*   bfB    = (u16*)alloc((size_t)NP * 64 * 2);  // y_p1_bf,  then h_p_bf
    float* h_p    = (float*)alloc((size_t)NP * 64 * 4);
    float* h_u    = (float*)alloc((size_t)NU * 64 * 4);

    // ---- CSR build: bucketed counting sort, both directions ----
    hipMemsetAsync(bcntP, 0, (size_t)MAXB * 2 * 4, stream);  // bcntP+bcntU contiguous
    k_histA<<<512, 256, 0, stream>>>(esrc, edst, bcntP, bcntU, NBP, NBU, E);
    k_scanBuckets<<<2, 256, 0, stream>>>(bcntP, basesP, curP, NBP, bcntU, basesU, curU, NBU);
    const int pblocks = (E + CHUNK - 1) / CHUNK;
    k_partition<<<pblocks, 256, 0, stream>>>(edst, esrc, curP, pairsP, NBP, E);  // dir P
    k_partition<<<pblocks, 256, 0, stream>>>(esrc, edst, curU, pairsU, NBU, E);  // dir U
    k_bucketFill<<<NBP + NBU, 256, 0, stream>>>(pairsP, basesP, NBP, nbr_p, deg_p, ptr_p, NP,
                                                pairsU, basesU, NBU, nbr_u, deg_u, ptr_u, NU);

    // ---- bf16 shadows for layer-1 aggregation sources ----
    k_cast8<<<(NU * 64 / 8 + 255) / 256, 256, 0, stream>>>(x_user, bfA, NU * 64 / 8);
    // bfB = bf16(x_product @ W1rl): persistent ctile, EMIT-only (static LDS 48.5 KB)
    {
        const int tiles = (NP + 31) / 32;
        k_ctile<128, 32, false, true, false, false, false><<<(tiles < 768 ? tiles : 768), 256, 0, stream>>>(
            nullptr, nullptr, x_product, W1rl, nullptr, bfB, NP);
    }

    const int tP64 = (NP + 63) / 64, tP32 = (NP + 31) / 32;
    const int tU64 = (NU + 63) / 64;
    auto cap = [](int t, int c) { return t < c ? t : c; };
    const int gP = cap(tP64, 512), gU = cap(tU64, 512);

    // ---- layer 1: fused dual gather, then combines ----
    k_gather2<<<(NP + NU + 3) / 4, 256, 0, stream>>>(bfA, nbr_p, ptr_p, deg_p, aggP, NP,
                                                     bfB, nbr_u, ptr_u, deg_u, aggU, NU);
    // h_p = relu(aggP@W1bl + b1b + x_product@W1br): two-pass (R5-proven shape)
    k_ctile<64, 64, false, false, false, true, true><<<cap(tP64, 1024), 256, 0, stream>>>(
        nullptr, b1b, aggP, W1bl, h_p, nullptr, NP);
    k_ctile<128, 32, true, true, true, false, true><<<cap(tP32, 768), 256, 0, stream>>>(
        h_p, nullptr, x_product, W1br, h_p, bfB, NP);
    // h_u = relu(aggU + b1r + x_user@W1rr), emit bfA
    k_ctile<64, 64, true, true, true, true, true><<<cap(tU64, 1024), 256, 0, stream>>>(
        aggU, b1r, x_user, W1rr, h_u, bfA, NU);

    // ---- layer 2: fused dual gather, then paired combines (2 dispatches) ----
    k_gather2<<<(NP + NU + 3) / 4, 256, 0, stream>>>(bfA, nbr_p, ptr_p, deg_p, aggP, NP,
                                                     bfB, nbr_u, ptr_u, deg_u, aggU, NU);
    // pass 1: aggP = aggP@W2bl + b2b  ||  aggU = aggU@W2rl + b2r
    k_ctilePair64<false, true><<<gP + gU, 256, 0, stream>>>(
        nullptr, b2b, aggP, W2bl, aggP, NP, gP,
        nullptr, b2r, aggU, W2rl, aggU, NU);
    // pass 2: h_p = aggP + h_p@W2br  ||  h_u = aggU + h_u@W2rr
    k_ctilePair64<true, false><<<gP + gU, 256, 0, stream>>>(
        aggP, nullptr, h_p, W2br, h_p, NP, gP,
        aggU, nullptr, h_u, W2rr, h_u, NU);

    // ---- classifier ----
    k_classify4<<<((EL + 3) / 4 + 3) / 4, 256, 0, stream>>>(h_u, h_p, lu, lp, (float*)d_out, EL);
}